// Round 13
// baseline (368.463 us; speedup 1.0000x reference)
//
#include <hip/hip_runtime.h>
#include <stdint.h>

typedef __attribute__((ext_vector_type(8))) short short8;
typedef __attribute__((ext_vector_type(4))) float f32x4;

__device__ __forceinline__ unsigned short f2bf(float f) {
    unsigned u = __float_as_uint(f);
    unsigned r = u + 0x7fffu + ((u >> 16) & 1u);   // RNE
    return (unsigned short)(r >> 16);
}
// monotone float<->uint encoding for atomicMax on floats
__device__ __forceinline__ unsigned fenc(float f) {
    unsigned u = __float_as_uint(f);
    return (u & 0x80000000u) ? ~u : (u | 0x80000000u);
}
__device__ __forceinline__ float fdec(unsigned e) {
    unsigned u = (e & 0x80000000u) ? (e & 0x7fffffffu) : ~e;
    return __uint_as_float(u);
}

// ---- x -> running fp32 x in d_out; W -> bf16 W^T; init s2 max slots ---------
__global__ __launch_bounds__(256) void k_init(const float* __restrict__ xin,
                                              const float* __restrict__ Wf,
                                              float* __restrict__ xq,
                                              unsigned short* __restrict__ wTb,
                                              unsigned* __restrict__ s2mx) {
    int blk = blockIdx.x, tid = threadIdx.x;
    if (blk < 2048) {
        int e0 = (blk * 256 + tid) * 4;
        *(f32x4*)(xq + e0) = *(const f32x4*)(xin + e0);
    } else if (blk < 2240) {
        int c = (blk - 2048) * 256 + tid;            // < 49152
        int l = c >> 14, rem = c & 16383, n = rem >> 7, k = rem & 127;
        wTb[c] = f2bf(Wf[l * 16384 + k * 128 + n]);  // wTb[l][n][k] = W[l][k][n]
    } else if (tid < 24) {
        s2mx[tid] = fenc(-3e38f);
    }
}

// ---- pack adj (int 0/1) to 64-bit masks: packed[row*32+wd] bit l = adj[row][wd*64+l]
__global__ __launch_bounds__(256) void k_pack(const int* __restrict__ adj,
                                              unsigned long long* __restrict__ packed) {
    int w = (blockIdx.x * 256 + threadIdx.x) >> 6;   // global wave id, 8192 waves
    int lane = threadIdx.x & 63;
    for (int k = 0; k < 64; k++) {
        int q = w * 64 + k;                           // word index 0..524287
        int row = q >> 5, wd = q & 31;
        int v = adj[row * 2048 + wd * 64 + lane];
        unsigned long long m = __ballot(v > 0);
        if (lane == 0) packed[q] = m;
    }
}

// ---- per layer: h = relu(x@W+b) via bf16 MFMA; s1,s2; batch max; H^T bf16 ---
__global__ __launch_bounds__(256) void k_h(
    const float* __restrict__ xq, const unsigned short* __restrict__ wTb,
    const float* __restrict__ bF, const float* __restrict__ aF, int layer,
    unsigned short* __restrict__ hT, float* __restrict__ s1g,
    float* __restrict__ s2g, unsigned* __restrict__ s2mx)
{
    __shared__ short xs[64 * 136];    // 17.4 KB, x tile bf16
    __shared__ short wsb[128 * 136];  // 34.8 KB, W^T tile bf16; reused for transpose
    __shared__ float s2blk[4];
    int blk = blockIdx.x, tid = threadIdx.x;
    int row0 = blk * 64, b = blk >> 5;
    int w = tid >> 6, lane = tid & 63, quad = lane >> 4, l15 = lane & 15;

    for (int c = tid; c < 1024; c += 256) {           // x: 64 rows x 128 k
        int r = c >> 4, kg = c & 15;
        const float* src = &xq[(row0 + r) * 128 + kg * 8];
        f32x4 v0 = *(const f32x4*)src;
        f32x4 v1 = *(const f32x4*)(src + 4);
        short8 o;
        o[0] = (short)f2bf(v0[0]); o[1] = (short)f2bf(v0[1]);
        o[2] = (short)f2bf(v0[2]); o[3] = (short)f2bf(v0[3]);
        o[4] = (short)f2bf(v1[0]); o[5] = (short)f2bf(v1[1]);
        o[6] = (short)f2bf(v1[2]); o[7] = (short)f2bf(v1[3]);
        *(short8*)&xs[r * 136 + kg * 8] = o;
    }
    const unsigned short* wl = wTb + layer * 16384;
    for (int c = tid; c < 2048; c += 256) {           // W^T: 128 n x 128 k
        int n = c >> 4, kg = c & 15;
        *(short8*)&wsb[n * 136 + kg * 8] = *(const short8*)&wl[n * 128 + kg * 8];
    }
    __syncthreads();

    f32x4 acc[8];
#pragma unroll
    for (int t = 0; t < 8; t++) acc[t] = {0.f, 0.f, 0.f, 0.f};
#pragma unroll
    for (int ks = 0; ks < 4; ks++) {
        short8 af = *(const short8*)&xs[(w * 16 + l15) * 136 + ks * 32 + quad * 8];
#pragma unroll
        for (int t = 0; t < 8; t++) {
            short8 bf = *(const short8*)&wsb[(t * 16 + l15) * 136 + ks * 32 + quad * 8];
            acc[t] = __builtin_amdgcn_mfma_f32_16x16x32_bf16(af, bf, acc[t], 0, 0, 0);
        }
    }

    // epilogue: bias+relu, s1/s2 row dots (reduce over l15 lanes via shfl)
    float s1p[4] = {0.f, 0.f, 0.f, 0.f}, s2p[4] = {0.f, 0.f, 0.f, 0.f};
#pragma unroll
    for (int t = 0; t < 8; t++) {
        int colg = t * 16 + l15;
        float bgf = bF[layer * 128 + colg];
        float a1 = aF[layer * 256 + colg];
        float a2 = aF[layer * 256 + 128 + colg];
#pragma unroll
        for (int r = 0; r < 4; r++) {
            float v = acc[t][r] + bgf;
            v = v > 0.f ? v : 0.f;
            acc[t][r] = v;
            s1p[r] = fmaf(v, a1, s1p[r]);
            s2p[r] = fmaf(v, a2, s2p[r]);
        }
    }
#pragma unroll
    for (int r = 0; r < 4; r++) {
#pragma unroll
        for (int off = 1; off < 16; off <<= 1) {
            s1p[r] += __shfl_xor(s1p[r], off, 64);
            s2p[r] += __shfl_xor(s2p[r], off, 64);
        }
    }
    if (l15 == 0) {
#pragma unroll
        for (int r = 0; r < 4; r++) {
            int rowg = row0 + w * 16 + quad * 4 + r;
            s1g[rowg] = s1p[r];
            s2g[rowg] = s2p[r];
        }
    }
    float mx = fmaxf(fmaxf(s2p[0], s2p[1]), fmaxf(s2p[2], s2p[3]));
    mx = fmaxf(mx, __shfl_xor(mx, 16, 64));
    mx = fmaxf(mx, __shfl_xor(mx, 32, 64));
    if (lane == 0) s2blk[w] = mx;
    __syncthreads();                  // all MFMA reads of wsb done; s2blk visible

    short* st = (short*)wsb;          // transpose buffer (64 x 130)
#pragma unroll
    for (int t = 0; t < 8; t++)
#pragma unroll
        for (int r = 0; r < 4; r++)
            st[(w * 16 + quad * 4 + r) * 130 + t * 16 + l15] = (short)f2bf(acc[t][r]);
    __syncthreads();
    if (tid == 0) {
        float m2 = fmaxf(fmaxf(s2blk[0], s2blk[1]), fmaxf(s2blk[2], s2blk[3]));
        atomicMax(&s2mx[layer * 8 + b], fenc(m2));
    }
    int i0 = (blk & 31) * 64;
    for (int c = tid; c < 1024; c += 256) {
        int d = c >> 3, ig = c & 7;
        short8 o;
#pragma unroll
        for (int ii = 0; ii < 8; ii++) o[ii] = st[(ig * 8 + ii) * 130 + d];
        *(short8*)&hT[(b * 128 + d) * 2048 + i0 + ig * 8] = o;
    }
}

// ---- per layer: flash P@H via MFMA over one j-half; partial O/psum out ------
// grid 512: blk = brow*2 + half. 256 threads = 4 waves = 4 row-strips of 16.
__global__ __launch_bounds__(256) void k_attn(
    const unsigned long long* __restrict__ packed,
    const unsigned short* __restrict__ hT, const float* __restrict__ s1g,
    const float* __restrict__ s2g, const unsigned* __restrict__ s2mx,
    int layer, float* __restrict__ Opart, float* __restrict__ Ppart)
{
    __shared__ short ht[144 * 72];               // 20.7 KB: d*72 + j, d=128 ones row
    __shared__ unsigned long long bits[64 * 32]; // 16 KB
    int blk = blockIdx.x, tid = threadIdx.x;
    int half = blk & 1, brow = blk >> 1;
    int b = brow >> 5;
    int rowg0 = brow * 64;
    int w = tid >> 6, lane = tid & 63, quad = lane >> 4, l15 = lane & 15;

    for (int c = tid; c < 2048; c += 256) bits[c] = packed[rowg0 * 32 + c];
    // static ones/zero rows (d = 128..143), written once
    for (int c = tid; c < 128; c += 256) {
        int d = 128 + (c >> 3), jg = c & 7;
        short8 v;
        short one = (short)0x3F80;
        if (d == 128) { v[0]=one;v[1]=one;v[2]=one;v[3]=one;v[4]=one;v[5]=one;v[6]=one;v[7]=one; }
        else { v[0]=0;v[1]=0;v[2]=0;v[3]=0;v[4]=0;v[5]=0;v[6]=0;v[7]=0; }
        *(short8*)&ht[d * 72 + jg * 8] = v;
    }

    int rowA = w * 16 + l15;                     // A-fragment row for this lane
    float s1v = s1g[rowg0 + rowA];
    float s2m = fdec(s2mx[layer * 8 + b]);
    float tmh = s1v + s2m;
    float mhat = fmaxf(tmh, 0.2f * tmh);         // leaky(s1 + max_b s2) >= all e
    f32x4 acc[9];
#pragma unroll
    for (int t = 0; t < 9; t++) acc[t] = {0.f, 0.f, 0.f, 0.f};

    // dynamic staging: exactly 4 short8 slots/thread (d<128 rows of the tile)
    int sd[4], sjg[4];
#pragma unroll
    for (int s = 0; s < 4; s++) {
        int c = tid + 256 * s;                   // 0..1023
        sd[s] = c >> 3; sjg[s] = c & 7;
    }
    short8 pv[4];
#pragma unroll
    for (int s = 0; s < 4; s++) {                // prefetch it=0
        int jts = half * 16;
        pv[s] = *(const short8*)&hT[(b * 128 + sd[s]) * 2048 + jts * 64 + sjg[s] * 8];
    }

    const float* s2b = s2g + b * 2048;
    for (int it = 0; it < 16; it++) {
#pragma unroll
        for (int s = 0; s < 4; s++)
            *(short8*)&ht[sd[s] * 72 + sjg[s] * 8] = pv[s];
        __syncthreads();
        if (it < 15) {                           // prefetch next; hides under MFMA
#pragma unroll
            for (int s = 0; s < 4; s++) {
                int jts = half * 16 + it + 1;
                pv[s] = *(const short8*)&hT[(b * 128 + sd[s]) * 2048 + jts * 64 + sjg[s] * 8];
            }
        }
        int jt = half * 16 + it;
        unsigned long long word = bits[rowA * 32 + jt];
#pragma unroll
        for (int ks = 0; ks < 2; ks++) {
            unsigned b8 = (unsigned)(word >> (ks * 32 + quad * 8)) & 0xffu;
            int jbase = jt * 64 + ks * 32 + quad * 8;
            f32x4 sa = *(const f32x4*)&s2b[jbase];
            f32x4 sb = *(const f32x4*)&s2b[jbase + 4];
            float sv[8] = {sa[0], sa[1], sa[2], sa[3], sb[0], sb[1], sb[2], sb[3]};
            short8 af;
#pragma unroll
            for (int jj = 0; jj < 8; jj++) {
                float e = s1v + sv[jj];
                e = fmaxf(e, 0.2f * e);                 // leaky_relu
                float pvv = __expf(e - mhat);
                pvv = (b8 & (1u << jj)) ? pvv : 0.f;    // adjacency mask
                af[jj] = (short)f2bf(pvv);
            }
#pragma unroll
            for (int t = 0; t < 9; t++) {               // t=8: ones column -> psum
                short8 bf = *(const short8*)&ht[(t * 16 + l15) * 72 + ks * 32 + quad * 8];
                acc[t] = __builtin_amdgcn_mfma_f32_16x16x32_bf16(af, bf, acc[t], 0, 0, 0);
            }
        }
        __syncthreads();
    }

    // write partial O and psum for this j-half (plain stores, no reduction)
#pragma unroll
    for (int r = 0; r < 4; r++) {
        int rowgC = rowg0 + w * 16 + quad * 4 + r;
        // ones-tile row-sum lands only in MFMA column n=0: broadcast from the
        // l15==0 lane of this quad
        float psum = __shfl(acc[8][r], lane & 48, 64);
        if (l15 == 0) Ppart[half * 16384 + rowgC] = psum;
#pragma unroll
        for (int t = 0; t < 8; t++)
            Opart[((size_t)half * 16384 + rowgC) * 128 + t * 16 + l15] = acc[t][r];
    }
}

// ---- combine halves: x += (O0+O1) / (p0+p1) ---------------------------------
__global__ __launch_bounds__(256) void k_comb(
    const float* __restrict__ Opart, const float* __restrict__ Ppart,
    float* __restrict__ xq)
{
    int idx = blockIdx.x * 256 + threadIdx.x;    // f32x4 index, 524288 total
    int row = idx >> 5;                          // 32 f32x4 per row
    float p = Ppart[row] + Ppart[16384 + row];
    float rl = p > 0.f ? 1.0f / p : 0.f;
    // halves are offset by 16384 rows * 128 = 2,097,152 FLOATS (R12 bug: *4)
    f32x4 o0 = *(const f32x4*)&Opart[(size_t)idx * 4];
    f32x4 o1 = *(const f32x4*)&Opart[(size_t)idx * 4 + 2097152];
    f32x4 xv = *(const f32x4*)&xq[idx * 4];
#pragma unroll
    for (int k = 0; k < 4; k++) xv[k] += (o0[k] + o1[k]) * rl;
    *(f32x4*)&xq[idx * 4] = xv;
}

extern "C" void kernel_launch(void* const* d_in, const int* in_sizes, int n_in,
                              void* d_out, int out_size, void* d_ws, size_t ws_size,
                              hipStream_t stream) {
    // adj = largest input; among the rest (excluding x = d_in[0]): W > attn_a > bg
    const void* px = d_in[0];
    int ia = 1; long amax = -1;
    for (int i = 1; i < n_in; i++)
        if ((long)in_sizes[i] > amax) { amax = in_sizes[i]; ia = i; }
    int rem[8]; int m = 0;
    for (int i = 1; i < n_in && m < 8; i++) if (i != ia) rem[m++] = i;
    for (int i = 0; i < m; i++)
        for (int j = i + 1; j < m; j++)
            if (in_sizes[rem[j]] > in_sizes[rem[i]]) { int t = rem[i]; rem[i] = rem[j]; rem[j] = t; }
    const int*   padj = (const int*)((n_in > 1) ? d_in[ia] : d_in[0]);
    const float* pW = (const float*)((m > 0) ? d_in[rem[0]] : d_in[0]);
    const float* pa = (const float*)((m > 1) ? d_in[rem[1]] : d_in[0]);
    const float* pb = (const float*)((m > 2) ? d_in[rem[2]] : d_in[0]);

    float* xq = (float*)d_out;                        // running fp32 x = output
    char* ws = (char*)d_ws;
    unsigned long long* packed = (unsigned long long*)ws;   // 4 MiB bitmask
    unsigned short* hT = (unsigned short*)(ws + 4194304);   // 4 MiB bf16 H^T
    float* s1 = (float*)(ws + 8388608);                     // 64 KiB
    float* s2 = (float*)(ws + 8454144);                     // 64 KiB
    unsigned* s2mx = (unsigned*)(ws + 8519680);             // 24 slots
    unsigned short* wTb = (unsigned short*)(ws + 8519808);  // 96 KiB bf16 W^T
    float* Opart = (float*)(ws + 16777216);                 // 16 MiB (2 halves)
    float* Ppart = (float*)(ws + 33554432);                 // 128 KiB (2 halves)

    k_init<<<2241, 256, 0, stream>>>((const float*)px, pW, xq, wTb, s2mx);
    k_pack<<<2048, 256, 0, stream>>>(padj, packed);
    for (int l = 0; l < 3; l++) {
        k_h<<<256, 256, 0, stream>>>(xq, wTb, pb, pa, l, hT, s1, s2, s2mx);
        k_attn<<<512, 256, 0, stream>>>(packed, hT, s1, s2, s2mx, l, Opart, Ppart);
        k_comb<<<2048, 256, 0, stream>>>(Opart, Ppart, xq);
    }
}